// Round 11
// baseline (471.395 us; speedup 1.0000x reference)
//
#include <hip/hip_runtime.h>
#include <math.h>

#define NPTS 262144
#define MT 128         // points per block

typedef __attribute__((ext_vector_type(8))) short bf16x8;
typedef __attribute__((ext_vector_type(4))) float f32x4;
typedef __attribute__((ext_vector_type(16))) float f32x16;
typedef __attribute__((ext_vector_type(2))) unsigned int u32x2;

#if defined(__has_builtin)
#if __has_builtin(__builtin_amdgcn_cvt_pk_bf16_f32)
#define HAVE_CVT_PK_BF16 1
#endif
#endif

__device__ __forceinline__ short f2bf(float f) {
    union { float f; unsigned u; } v; v.f = f;
    unsigned r = v.u + 0x7fffu + ((v.u >> 16) & 1u);   // RNE
    return (short)(r >> 16);
}
__device__ __forceinline__ unsigned pk2(float a, float b) {
#ifdef HAVE_CVT_PK_BF16
    auto r = __builtin_amdgcn_cvt_pk_bf16_f32(a, b);   // 1 instr, RNE
    unsigned u; __builtin_memcpy(&u, &r, 4);
    return u;
#else
    return ((unsigned)(unsigned short)f2bf(a)) |
           ((unsigned)(unsigned short)f2bf(b) << 16);
#endif
}

// LDS-only barrier: drains ds ops (X producer->consumer hazard) but leaves
// global loads IN FLIGHT across the barrier (no vmcnt(0) drain).
__device__ __forceinline__ void barrier_lds() {
    asm volatile("s_waitcnt lgkmcnt(0)" ::: "memory");
    __builtin_amdgcn_s_barrier();
}

// ---- swizzled-weight workspace layout (offsets in bf16 elements) ----
// All big layers in 32x32x16 fragment format; density + r2 keep 16x16x32.
#define OFF_IN   0
#define SZ_IN    (64*256)
#define OFF_H0   (OFF_IN + SZ_IN)
#define SZ_H     (256*256)
#define OFF_H1   (OFF_H0 + SZ_H)
#define OFF_H2   (OFF_H1 + SZ_H)
#define OFF_H3   (OFF_H2 + SZ_H)
#define OFF_H4   (OFF_H3 + SZ_H)
#define SZ_H4    (320*256)
#define OFF_H5   (OFF_H4 + SZ_H4)
#define OFF_H6   (OFF_H5 + SZ_H)
#define OFF_OUT  (OFF_H6 + SZ_H)
#define SZ_OUTM  (256*256)          // out features, 32-fmt
#define OFF_OUTD (OFF_OUT + SZ_OUTM)
#define SZ_OUTD  (256*16)           // density column, 16-fmt (n=0 real)
#define OFF_R1   (OFF_OUTD + SZ_OUTD)
#define SZ_R1    (288*128)
#define OFF_R2   (OFF_R1 + SZ_R1)
#define SZ_R2    (128*16)
#define WS_TOTAL (OFF_R2 + SZ_R2)

// ---------------- weight prep: f32 -> bf16, fragment swizzle ----------------
// 32-fmt tile (kt,nb): elem ((kt*nNb + nb)*64 + L)*8 + j
//   holds W[kt*16 + (L>>5)*8 + j][nb*32 + (L&31)]  (0-padded)
//   -> A operand of A=W^T: A[n=lane&31][k=(lane>>5)*8+j].
// 16-fmt tile (kt,nt): elem ((kt*nNt + nt)*64 + L)*8 + j
//   holds W[kt*32 + (L>>4)*8 + j][nt*16 + (L&15)].
struct PrepP { const float* W[11]; short* ws; };

__global__ __launch_bounds__(256) void prep_all(PrepP pp) {
    int i = blockIdx.x * 256 + threadIdx.x;
    if (i >= WS_TOTAL) return;
    const int offs[13] = {OFF_IN, OFF_H0, OFF_H1, OFF_H2, OFF_H3, OFF_H4,
                          OFF_H5, OFF_H6, OFF_OUT, OFF_OUTD, OFF_R1, OFF_R2,
                          WS_TOTAL};
    const int wsrc[12] = {0,1,2,3,4,5,6,7,8,8,9,10};
    const int Ks[12]   = {63,256,256,256,256,319,256,256,256,256,283,128};
    const int Nsrc[12] = {256,256,256,256,256,256,256,256,257,257,128,3};
    int seg = 0;
    while (i >= offs[seg + 1]) seg++;
    int li = i - offs[seg];
    int j = li & 7, L = (li >> 3) & 63, tile = li >> 9;
    const float* W = pp.W[wsrc[seg]];
    float v = 0.f;
    if (seg == 9) {                        // density: 16-fmt, frag n==0 <- col 256
        int k = tile * 32 + ((L >> 4) << 3) + j;
        if (k < 256 && (L & 15) == 0) v = W[k * 257 + 256];
    } else if (seg == 11) {                // r2: 16-fmt, N=3
        int k = tile * 32 + ((L >> 4) << 3) + j;
        int n = L & 15;
        if (k < 128 && n < 3) v = W[k * 3 + n];
    } else {                               // 32-fmt
        int nNb = (seg == 10) ? 4 : 8;
        int nb = tile % nNb, kt = tile / nNb;
        int k = kt * 16 + ((L >> 5) << 3) + j;
        int n = nb * 32 + (L & 31);
        if (k < Ks[seg]) v = W[k * Nsrc[seg] + n];
    }
    pp.ws[i] = f2bf(v);
}

// ---------------- fused MLP ----------------
struct Params {
    const float *pos, *dir;
    const float *b_in, *b_h0, *b_h1, *b_h2, *b_h3, *b_h4, *b_h5, *b_h6;
    const float *b_out, *b_r1, *b_r2;
    const short *w;
    float *out;
};

// X LDS: single in-place buffer, MT=128 points. k-grouped B-fragment layout:
// element (k,m) of activation X[m][k] at short index ((k>>3)*128 + m)*8 + (k&7).
// 40 groups x 128 pts x 16B = 81920 B exact -> 2 blocks/CU at 512 thr.
//
// R11 = R4 grid (the lattice optimum: exclusive-A nb=wave keeps L2 demand
// ~32 B/cyc/CU under the ~56 ceiling; MT=128 required for that; LDS then
// saturates ~128 B/cyc) + DIST-2 B PREFETCH: at full LDS saturation the
// read queue delay is ~16 waves x 4 reads x 8 cyc ~ 512 cyc = exactly the
// dist-1 window -> B-frags arrive marginally late every kt (MfmaUtil pinned
// ~47%). dist-2 doubles the window to ~1024 cyc. Cost: +16 VGPRs.
//
// In-place layer: [issue kt0+kt1 A loads] BAR1 (LDS-only drain; loads stay
// in flight) [K-loop reads X] BAR2 [epilogue writes X in place].
// a-prefetch dist-2 (alternating a0/a1), b-prefetch dist-2 (b_c/b_m/b_n).
// 32x32x16 MFMA: A = W^T (32 n x 16 k), B = X^T (16 k x 32 m).
// C (verified m74/m101): col(m)=lane&31, row(n)=(reg&3)+8*(reg>>2)+4*(lane>>5).
// MODE 0: relu. MODE 1: out layer: features (no relu); density row via 16x16
// pre-pass (all 8 waves, m-tile = wave, OFF_OUTD region) straight to gmem.
template<int NKT, int NNB, int TM, int MODE>
__device__ __forceinline__ void layer32(const short* __restrict__ Wsw,
                                        const short* __restrict__ Wd,
                                        const float* __restrict__ bias,
                                        short* X, float* dout, int p0,
                                        int nb, int mbB, int wave, int lane) {
    const int l31 = lane & 31, hi = lane >> 5;
    const short* xb = X + hi * 1024 + (mbB * 32 + l31) * 8;  // + t*256 + kt*2048
    const short* wp = Wsw + (size_t)(nb * 64 + lane) * 8;    // + kt*NNB*512

    // pre-barrier: kt0 + kt1 A fragments (global; in flight across BAR1)
    bf16x8 a0 = *(const bf16x8*)(wp);
    bf16x8 a1 = *(const bf16x8*)(wp + (size_t)NNB * 512);

    barrier_lds();                        // BAR1: X inputs published

    if (MODE == 1) {                      // density pre-pass (16-fmt region)
        const int l15 = lane & 15, quad = lane >> 4;
        const short* xd = X + quad * 1024 + (wave * 16 + l15) * 8;
        f32x4 ad = (f32x4){0.f, 0.f, 0.f, 0.f};
#pragma unroll
        for (int kt = 0; kt < 8; ++kt) {
            bf16x8 b = *(const bf16x8*)(xd + kt * 4096);
            bf16x8 a = *(const bf16x8*)(Wd + (size_t)(kt * 64 + lane) * 8);
            ad = __builtin_amdgcn_mfma_f32_16x16x32_bf16(a, b, ad, 0, 0, 0);
        }
        if (quad == 0)                    // C row 0 = n 256 (density)
            dout[3 * NPTS + p0 + wave * 16 + l15] = fmaxf(ad[0] + bias[256], 0.f);
    }

    f32x16 acc[TM];
#pragma unroll
    for (int t = 0; t < TM; t++)
#pragma unroll
        for (int r = 0; r < 16; r++) acc[t][r] = 0.f;

    // dist-2 B pipeline: b_c = kt, b_m = kt+1, b_n = incoming kt+2
    bf16x8 b_c[TM], b_m[TM];
#pragma unroll
    for (int t = 0; t < TM; t++)
        b_c[t] = *(const bf16x8*)(xb + t * 256);
#pragma unroll
    for (int t = 0; t < TM; t++)
        b_m[t] = *(const bf16x8*)(xb + 2048 + t * 256);

#pragma unroll
    for (int kt = 0; kt < NKT; ++kt) {
        bf16x8 b_n[TM], a_n;
        if (kt + 2 < NKT) {
#pragma unroll
            for (int t = 0; t < TM; t++)
                b_n[t] = *(const bf16x8*)(xb + (kt + 2) * 2048 + t * 256);
            a_n = *(const bf16x8*)(wp + (size_t)(kt + 2) * NNB * 512);
        }
        if ((kt & 1) == 0) {
#pragma unroll
            for (int t = 0; t < TM; t++)
                acc[t] = __builtin_amdgcn_mfma_f32_32x32x16_bf16(a0, b_c[t], acc[t], 0, 0, 0);
        } else {
#pragma unroll
            for (int t = 0; t < TM; t++)
                acc[t] = __builtin_amdgcn_mfma_f32_32x32x16_bf16(a1, b_c[t], acc[t], 0, 0, 0);
        }
        if (kt + 2 < NKT) {
            if ((kt & 1) == 0) a0 = a_n; else a1 = a_n;
        }
        if (kt + 1 < NKT) {
#pragma unroll
            for (int t = 0; t < TM; t++) b_c[t] = b_m[t];
        }
        if (kt + 2 < NKT) {
#pragma unroll
            for (int t = 0; t < TM; t++) b_m[t] = b_n[t];
        }
    }

    barrier_lds();                        // BAR2: all reads of X done

    // epilogue -> X in place. n = 32nb + 8rq + 4hi + r.
#pragma unroll
    for (int t = 0; t < TM; t++) {
        const int m = (mbB + t) * 32 + l31;
#pragma unroll
        for (int rq = 0; rq < 4; rq++) {
            const int nbase = nb * 32 + rq * 8 + hi * 4;
            const f32x4 bv = *(const f32x4*)(bias + nbase);
            float v0 = acc[t][rq * 4 + 0] + bv[0];
            float v1 = acc[t][rq * 4 + 1] + bv[1];
            float v2 = acc[t][rq * 4 + 2] + bv[2];
            float v3 = acc[t][rq * 4 + 3] + bv[3];
            if (MODE == 0) {
                v0 = fmaxf(v0, 0.f); v1 = fmaxf(v1, 0.f);
                v2 = fmaxf(v2, 0.f); v3 = fmaxf(v3, 0.f);
            }
            u32x2 w; w[0] = pk2(v0, v1); w[1] = pk2(v2, v3);
            *(u32x2*)(X + (size_t)(nb * 4 + rq) * 1024 + m * 8 + hi * 4) = w;
        }
    }
}

__global__ __launch_bounds__(512, 4) void nerf_fused(Params P) {
    __shared__ __align__(16) short X[40 * 1024];   // 81920 B exact
    const int tid = threadIdx.x;
    const int wave = tid >> 6, lane = tid & 63;
    const int p0 = blockIdx.x * MT;

    // ---- positional encoding: item = (pt, k-group) -> 8 cols, b128 stores ----
    for (int i = tid; i < 128 * 8; i += 512) {
        const int pt = i & 127, g = i >> 7;       // g = 0..7
        const float x0 = P.pos[(p0 + pt) * 3 + 0];
        const float x1 = P.pos[(p0 + pt) * 3 + 1];
        const float x2 = P.pos[(p0 + pt) * 3 + 2];
        bf16x8 v;
#pragma unroll
        for (int j = 0; j < 8; j++) {
            const int d = g * 8 + j;
            float val = 0.f;
            if (d < 3) val = (d == 0) ? x0 : (d == 1) ? x1 : x2;
            else if (d < 63) {
                const int e = d - 3, f = e / 6, r = e % 6;
                const float x = (r % 3 == 0) ? x0 : (r % 3 == 1) ? x1 : x2;
                const float xf = x * (float)(1 << f);
                val = (r < 3) ? sinf(xf) : cosf(xf);
            }
            v[j] = f2bf(val);
        }
        *(bf16x8*)(X + ((size_t)g * 128 + pt) * 8) = v;          // input cols
        *(bf16x8*)(X + ((size_t)(32 + g) * 128 + pt) * 8) = v;   // h4 skip copy
    }

    // hidden/out: 8 waves, each nb = wave (exclusive A), all 4 m-blocks
    layer32< 4, 8, 4, 0>(P.w + OFF_IN, nullptr, P.b_in, X, P.out, p0, wave, 0, wave, lane);
    layer32<16, 8, 4, 0>(P.w + OFF_H0, nullptr, P.b_h0, X, P.out, p0, wave, 0, wave, lane);
    layer32<16, 8, 4, 0>(P.w + OFF_H1, nullptr, P.b_h1, X, P.out, p0, wave, 0, wave, lane);
    layer32<16, 8, 4, 0>(P.w + OFF_H2, nullptr, P.b_h2, X, P.out, p0, wave, 0, wave, lane);
    layer32<16, 8, 4, 0>(P.w + OFF_H3, nullptr, P.b_h3, X, P.out, p0, wave, 0, wave, lane);
    layer32<20, 8, 4, 0>(P.w + OFF_H4, nullptr, P.b_h4, X, P.out, p0, wave, 0, wave, lane); // concat

    // DE recompute + splice into groups 32..35: h4's BAR2 closed all reads
    // of 32..39; h4's epilogue writes only groups 0..31; h5's BAR1 publishes
    // both. Cols 283..287 stay real zeros (weights zero-padded there too).
    {
        const int ptD = tid & 127, gD = tid >> 7;     // gD = 0..3
        const float x0 = P.dir[(p0 + ptD) * 3 + 0];
        const float x1 = P.dir[(p0 + ptD) * 3 + 1];
        const float x2 = P.dir[(p0 + ptD) * 3 + 2];
        bf16x8 de_v;
#pragma unroll
        for (int j = 0; j < 8; j++) {
            const int d = gD * 8 + j;
            float val = 0.f;
            if (d < 3) val = (d == 0) ? x0 : (d == 1) ? x1 : x2;
            else if (d < 27) {
                const int e = d - 3, f = e / 6, r = e % 6;
                const float x = (r % 3 == 0) ? x0 : (r % 3 == 1) ? x1 : x2;
                const float xf = x * (float)(1 << f);
                val = (r < 3) ? sinf(xf) : cosf(xf);
            }
            de_v[j] = f2bf(val);
        }
        *(bf16x8*)(X + ((size_t)(32 + gD) * 128 + ptD) * 8) = de_v;
    }

    layer32<16, 8, 4, 0>(P.w + OFF_H5, nullptr, P.b_h5, X, P.out, p0, wave, 0, wave, lane);
    layer32<16, 8, 4, 0>(P.w + OFF_H6, nullptr, P.b_h6, X, P.out, p0, wave, 0, wave, lane);
    layer32<16, 8, 4, 1>(P.w + OFF_OUT, P.w + OFF_OUTD, P.b_out, X, P.out, p0, wave, 0, wave, lane);

    // r1 (K=288 -> 128): nb = wave&3, m-half = wave>>2 (TM=2 m-blocks each)
    layer32<18, 4, 2, 0>(P.w + OFF_R1, nullptr, P.b_r1, X, P.out, p0, wave & 3, (wave >> 2) * 2, wave, lane);

    // ---- r2 (128 -> 3) + sigmoid; 16x16, 8 waves, one 16-pt tile each ----
    barrier_lds();
    {
        const int l15 = lane & 15, quad = lane >> 4;
        const short* xb = X + quad * 1024 + (wave * 16 + l15) * 8;
        bf16x8 a0 = *(const bf16x8*)(P.w + OFF_R2 + (size_t)(0 * 64 + lane) * 8);
        bf16x8 a1 = *(const bf16x8*)(P.w + OFF_R2 + (size_t)(1 * 64 + lane) * 8);
        bf16x8 a2 = *(const bf16x8*)(P.w + OFF_R2 + (size_t)(2 * 64 + lane) * 8);
        bf16x8 a3 = *(const bf16x8*)(P.w + OFF_R2 + (size_t)(3 * 64 + lane) * 8);
        f32x4 acc = (f32x4){0.f, 0.f, 0.f, 0.f};
        bf16x8 b0 = *(const bf16x8*)(xb);
        bf16x8 b1 = *(const bf16x8*)(xb + 4096);
        bf16x8 b2 = *(const bf16x8*)(xb + 8192);
        bf16x8 b3 = *(const bf16x8*)(xb + 12288);
        acc = __builtin_amdgcn_mfma_f32_16x16x32_bf16(a0, b0, acc, 0, 0, 0);
        acc = __builtin_amdgcn_mfma_f32_16x16x32_bf16(a1, b1, acc, 0, 0, 0);
        acc = __builtin_amdgcn_mfma_f32_16x16x32_bf16(a2, b2, acc, 0, 0, 0);
        acc = __builtin_amdgcn_mfma_f32_16x16x32_bf16(a3, b3, acc, 0, 0, 0);
        if (quad == 0) {                   // rows r = rgb channel
#pragma unroll
            for (int r = 0; r < 3; r++) {
                const float v = acc[r] + P.b_r2[r];
                P.out[(size_t)(p0 + wave * 16 + l15) * 3 + r] = 1.f / (1.f + expf(-v));
            }
        }
    }
}

extern "C" void kernel_launch(void* const* d_in, const int* in_sizes, int n_in,
                              void* d_out, int out_size, void* d_ws, size_t ws_size,
                              hipStream_t stream) {
    short* ws = (short*)d_ws;

    PrepP pp;
    pp.W[0]  = (const float*)d_in[2];   // W_in
    pp.W[1]  = (const float*)d_in[4];   // W_h0
    pp.W[2]  = (const float*)d_in[6];   // W_h1
    pp.W[3]  = (const float*)d_in[8];   // W_h2
    pp.W[4]  = (const float*)d_in[10];  // W_h3
    pp.W[5]  = (const float*)d_in[12];  // W_h4
    pp.W[6]  = (const float*)d_in[14];  // W_h5
    pp.W[7]  = (const float*)d_in[16];  // W_h6
    pp.W[8]  = (const float*)d_in[18];  // W_out
    pp.W[9]  = (const float*)d_in[20];  // W_r1
    pp.W[10] = (const float*)d_in[22];  // W_r2
    pp.ws = ws;
    hipLaunchKernelGGL(prep_all, dim3((WS_TOTAL + 255) / 256), dim3(256), 0, stream, pp);

    Params P;
    P.pos  = (const float*)d_in[0];
    P.dir  = (const float*)d_in[1];
    P.b_in = (const float*)d_in[3];
    P.b_h0 = (const float*)d_in[5];
    P.b_h1 = (const float*)d_in[7];
    P.b_h2 = (const float*)d_in[9];
    P.b_h3 = (const float*)d_in[11];
    P.b_h4 = (const float*)d_in[13];
    P.b_h5 = (const float*)d_in[15];
    P.b_h6 = (const float*)d_in[17];
    P.b_out = (const float*)d_in[19];
    P.b_r1 = (const float*)d_in[21];
    P.b_r2 = (const float*)d_in[23];
    P.w = ws;
    P.out = (float*)d_out;
    hipLaunchKernelGGL(nerf_fused, dim3(NPTS / MT), dim3(512), 0, stream, P);
}

// Round 12
// 399.163 us; speedup vs baseline: 1.1810x; 1.1810x over previous
//
#include <hip/hip_runtime.h>
#include <math.h>

#define NPTS 262144
#define MT 128         // points per block

typedef __attribute__((ext_vector_type(8))) short bf16x8;
typedef __attribute__((ext_vector_type(4))) float f32x4;
typedef __attribute__((ext_vector_type(16))) float f32x16;
typedef __attribute__((ext_vector_type(2))) unsigned int u32x2;

#if defined(__has_builtin)
#if __has_builtin(__builtin_amdgcn_cvt_pk_bf16_f32)
#define HAVE_CVT_PK_BF16 1
#endif
#endif

__device__ __forceinline__ short f2bf(float f) {
    union { float f; unsigned u; } v; v.f = f;
    unsigned r = v.u + 0x7fffu + ((v.u >> 16) & 1u);   // RNE
    return (short)(r >> 16);
}
__device__ __forceinline__ unsigned pk2(float a, float b) {
#ifdef HAVE_CVT_PK_BF16
    auto r = __builtin_amdgcn_cvt_pk_bf16_f32(a, b);   // 1 instr, RNE
    unsigned u; __builtin_memcpy(&u, &r, 4);
    return u;
#else
    return ((unsigned)(unsigned short)f2bf(a)) |
           ((unsigned)(unsigned short)f2bf(b) << 16);
#endif
}

// ---- swizzled-weight workspace layout (offsets in bf16 elements) ----
// All big layers in 32x32x16 fragment format; density + r2 keep 16x16x32.
#define OFF_IN   0
#define SZ_IN    (64*256)
#define OFF_H0   (OFF_IN + SZ_IN)
#define SZ_H     (256*256)
#define OFF_H1   (OFF_H0 + SZ_H)
#define OFF_H2   (OFF_H1 + SZ_H)
#define OFF_H3   (OFF_H2 + SZ_H)
#define OFF_H4   (OFF_H3 + SZ_H)
#define SZ_H4    (320*256)
#define OFF_H5   (OFF_H4 + SZ_H4)
#define OFF_H6   (OFF_H5 + SZ_H)
#define OFF_OUT  (OFF_H6 + SZ_H)
#define SZ_OUTM  (256*256)          // out features, 32-fmt
#define OFF_OUTD (OFF_OUT + SZ_OUTM)
#define SZ_OUTD  (256*16)           // density column, 16-fmt (n=0 real)
#define OFF_R1   (OFF_OUTD + SZ_OUTD)
#define SZ_R1    (288*128)
#define OFF_R2   (OFF_R1 + SZ_R1)
#define SZ_R2    (128*16)
#define WS_TOTAL (OFF_R2 + SZ_R2)

// ---------------- weight prep: f32 -> bf16, fragment swizzle ----------------
// 32-fmt tile (kt,nb): elem ((kt*nNb + nb)*64 + L)*8 + j
//   holds W[kt*16 + (L>>5)*8 + j][nb*32 + (L&31)]  (0-padded)
//   -> A operand of A=W^T: A[n=lane&31][k=(lane>>5)*8+j].
// 16-fmt tile (kt,nt): elem ((kt*nNt + nt)*64 + L)*8 + j
//   holds W[kt*32 + (L>>4)*8 + j][nt*16 + (L&15)].
struct PrepP { const float* W[11]; short* ws; };

__global__ __launch_bounds__(256) void prep_all(PrepP pp) {
    int i = blockIdx.x * 256 + threadIdx.x;
    if (i >= WS_TOTAL) return;
    const int offs[13] = {OFF_IN, OFF_H0, OFF_H1, OFF_H2, OFF_H3, OFF_H4,
                          OFF_H5, OFF_H6, OFF_OUT, OFF_OUTD, OFF_R1, OFF_R2,
                          WS_TOTAL};
    const int wsrc[12] = {0,1,2,3,4,5,6,7,8,8,9,10};
    const int Ks[12]   = {63,256,256,256,256,319,256,256,256,256,283,128};
    const int Nsrc[12] = {256,256,256,256,256,256,256,256,257,257,128,3};
    int seg = 0;
    while (i >= offs[seg + 1]) seg++;
    int li = i - offs[seg];
    int j = li & 7, L = (li >> 3) & 63, tile = li >> 9;
    const float* W = pp.W[wsrc[seg]];
    float v = 0.f;
    if (seg == 9) {                        // density: 16-fmt, frag n==0 <- col 256
        int k = tile * 32 + ((L >> 4) << 3) + j;
        if (k < 256 && (L & 15) == 0) v = W[k * 257 + 256];
    } else if (seg == 11) {                // r2: 16-fmt, N=3
        int k = tile * 32 + ((L >> 4) << 3) + j;
        int n = L & 15;
        if (k < 128 && n < 3) v = W[k * 3 + n];
    } else {                               // 32-fmt
        int nNb = (seg == 10) ? 4 : 8;
        int nb = tile % nNb, kt = tile / nNb;
        int k = kt * 16 + ((L >> 5) << 3) + j;
        int n = nb * 32 + (L & 31);
        if (k < Ks[seg]) v = W[k * Nsrc[seg] + n];
    }
    pp.ws[i] = f2bf(v);
}

// ---------------- fused MLP ----------------
struct Params {
    const float *pos, *dir;
    const float *b_in, *b_h0, *b_h1, *b_h2, *b_h3, *b_h4, *b_h5, *b_h6;
    const float *b_out, *b_r1, *b_r2;
    const short *w;
    float *out;
};

// X LDS: single in-place buffer, MT=128 points. k-grouped B-fragment layout:
// element (k,m) of activation X[m][k] at short index ((k>>3)*128 + m)*8 + (k&7).
// 40 groups x 128 pts x 16B = 81920 B exact -> 2 blocks/CU at 512 thr.
// Groups 0..31 = 256 activation cols; 32..39 = PE skip copy, later DE.
//
// R12 = the round-4 measured optimum (318us; all 7 structural departures
// R5-R11 regressed or tied) + T5 s_setprio around the MFMA cluster.
// Lattice summary (per-CU): MFMA ~125us (32cyc/mfma), X-from-LDS ~170us at
// ~100B/cyc, A-from-L2 ~70us; exclusive-A (nb=wave) keeps L2 <~32B/cyc;
// dist-2 prefetch cannot fit the 128-VGPR cap (R11 spilled).
//
// In-place layer: [issue kt0+kt1 A loads] BAR1 [K-loop reads X] BAR2
// [epilogue writes X in place]. a-prefetch dist-2 (alternating a0/a1),
// b-prefetch dist-1. 32x32x16 MFMA: A = W^T, B = X^T.
// C (verified m74/m101): col(m)=lane&31, row(n)=(reg&3)+8*(reg>>2)+4*(lane>>5).
// MODE 0: relu. MODE 1: out layer: features (no relu); density row via 16x16
// pre-pass (all 8 waves, m-tile = wave, OFF_OUTD region) straight to gmem.
template<int NKT, int NNB, int TM, int MODE>
__device__ __forceinline__ void layer32(const short* __restrict__ Wsw,
                                        const short* __restrict__ Wd,
                                        const float* __restrict__ bias,
                                        short* X, float* dout, int p0,
                                        int nb, int mbB, int wave, int lane) {
    const int l31 = lane & 31, hi = lane >> 5;
    const short* xb = X + hi * 1024 + (mbB * 32 + l31) * 8;  // + t*256 + kt*2048
    const short* wp = Wsw + (size_t)(nb * 64 + lane) * 8;    // + kt*NNB*512

    // pre-barrier: first two k-tiles of weights (global; latency overlaps
    // barrier arrival)
    bf16x8 a0 = *(const bf16x8*)(wp);
    bf16x8 a1 = *(const bf16x8*)(wp + (size_t)NNB * 512);

    __syncthreads();                      // BAR1: X inputs published

    if (MODE == 1) {                      // density pre-pass (16-fmt region)
        const int l15 = lane & 15, quad = lane >> 4;
        const short* xd = X + quad * 1024 + (wave * 16 + l15) * 8;
        f32x4 ad = (f32x4){0.f, 0.f, 0.f, 0.f};
#pragma unroll
        for (int kt = 0; kt < 8; ++kt) {
            bf16x8 b = *(const bf16x8*)(xd + kt * 4096);
            bf16x8 a = *(const bf16x8*)(Wd + (size_t)(kt * 64 + lane) * 8);
            ad = __builtin_amdgcn_mfma_f32_16x16x32_bf16(a, b, ad, 0, 0, 0);
        }
        if (quad == 0)                    // C row 0 = n 256 (density)
            dout[3 * NPTS + p0 + wave * 16 + l15] = fmaxf(ad[0] + bias[256], 0.f);
    }

    f32x16 acc[TM];
#pragma unroll
    for (int t = 0; t < TM; t++)
#pragma unroll
        for (int r = 0; r < 16; r++) acc[t][r] = 0.f;

    bf16x8 b_c[TM];
#pragma unroll
    for (int t = 0; t < TM; t++)
        b_c[t] = *(const bf16x8*)(xb + t * 256);

#pragma unroll
    for (int kt = 0; kt < NKT; ++kt) {
        bf16x8 b_n[TM], a_n;
        if (kt + 1 < NKT) {
#pragma unroll
            for (int t = 0; t < TM; t++)
                b_n[t] = *(const bf16x8*)(xb + (kt + 1) * 2048 + t * 256);
        }
        if (kt + 2 < NKT)
            a_n = *(const bf16x8*)(wp + (size_t)(kt + 2) * NNB * 512);
        __builtin_amdgcn_s_setprio(1);    // favor this wave while in MFMA
        if ((kt & 1) == 0) {
#pragma unroll
            for (int t = 0; t < TM; t++)
                acc[t] = __builtin_amdgcn_mfma_f32_32x32x16_bf16(a0, b_c[t], acc[t], 0, 0, 0);
        } else {
#pragma unroll
            for (int t = 0; t < TM; t++)
                acc[t] = __builtin_amdgcn_mfma_f32_32x32x16_bf16(a1, b_c[t], acc[t], 0, 0, 0);
        }
        __builtin_amdgcn_s_setprio(0);
        if (kt + 2 < NKT) {
            if ((kt & 1) == 0) a0 = a_n; else a1 = a_n;
        }
        if (kt + 1 < NKT) {
#pragma unroll
            for (int t = 0; t < TM; t++) b_c[t] = b_n[t];
        }
    }

    __syncthreads();                      // BAR2: all reads of X done

    // epilogue -> X in place. n = 32nb + 8rq + 4hi + r.
#pragma unroll
    for (int t = 0; t < TM; t++) {
        const int m = (mbB + t) * 32 + l31;
#pragma unroll
        for (int rq = 0; rq < 4; rq++) {
            const int nbase = nb * 32 + rq * 8 + hi * 4;
            const f32x4 bv = *(const f32x4*)(bias + nbase);
            float v0 = acc[t][rq * 4 + 0] + bv[0];
            float v1 = acc[t][rq * 4 + 1] + bv[1];
            float v2 = acc[t][rq * 4 + 2] + bv[2];
            float v3 = acc[t][rq * 4 + 3] + bv[3];
            if (MODE == 0) {
                v0 = fmaxf(v0, 0.f); v1 = fmaxf(v1, 0.f);
                v2 = fmaxf(v2, 0.f); v3 = fmaxf(v3, 0.f);
            }
            u32x2 w; w[0] = pk2(v0, v1); w[1] = pk2(v2, v3);
            *(u32x2*)(X + (size_t)(nb * 4 + rq) * 1024 + m * 8 + hi * 4) = w;
        }
    }
}

__global__ __launch_bounds__(512, 4) void nerf_fused(Params P) {
    __shared__ __align__(16) short X[40 * 1024];   // 81920 B exact
    const int tid = threadIdx.x;
    const int wave = tid >> 6, lane = tid & 63;
    const int p0 = blockIdx.x * MT;

    // ---- positional encoding: item = (pt, k-group) -> 8 cols, b128 stores ----
    for (int i = tid; i < 128 * 8; i += 512) {
        const int pt = i & 127, g = i >> 7;       // g = 0..7
        const float x0 = P.pos[(p0 + pt) * 3 + 0];
        const float x1 = P.pos[(p0 + pt) * 3 + 1];
        const float x2 = P.pos[(p0 + pt) * 3 + 2];
        bf16x8 v;
#pragma unroll
        for (int j = 0; j < 8; j++) {
            const int d = g * 8 + j;
            float val = 0.f;
            if (d < 3) val = (d == 0) ? x0 : (d == 1) ? x1 : x2;
            else if (d < 63) {
                const int e = d - 3, f = e / 6, r = e % 6;
                const float x = (r % 3 == 0) ? x0 : (r % 3 == 1) ? x1 : x2;
                const float xf = x * (float)(1 << f);
                val = (r < 3) ? sinf(xf) : cosf(xf);
            }
            v[j] = f2bf(val);
        }
        *(bf16x8*)(X + ((size_t)g * 128 + pt) * 8) = v;          // input cols
        *(bf16x8*)(X + ((size_t)(32 + g) * 128 + pt) * 8) = v;   // h4 skip copy
    }

    // ---- dir encoding into registers (1 group per thread: 128 pts x 4 grp);
    //      spliced into groups 32..35 once h4's reads are closed ----
    bf16x8 de_v;
    const int ptD = tid & 127, gD = tid >> 7;     // gD = 0..3
    {
        const float x0 = P.dir[(p0 + ptD) * 3 + 0];
        const float x1 = P.dir[(p0 + ptD) * 3 + 1];
        const float x2 = P.dir[(p0 + ptD) * 3 + 2];
#pragma unroll
        for (int j = 0; j < 8; j++) {
            const int d = gD * 8 + j;
            float val = 0.f;
            if (d < 3) val = (d == 0) ? x0 : (d == 1) ? x1 : x2;
            else if (d < 27) {
                const int e = d - 3, f = e / 6, r = e % 6;
                const float x = (r % 3 == 0) ? x0 : (r % 3 == 1) ? x1 : x2;
                const float xf = x * (float)(1 << f);
                val = (r < 3) ? sinf(xf) : cosf(xf);
            }
            de_v[j] = f2bf(val);
        }
    }

    // hidden/out: 8 waves, each nb = wave (32 n), all 4 m-blocks (128 pts)
    layer32< 4, 8, 4, 0>(P.w + OFF_IN, nullptr, P.b_in, X, P.out, p0, wave, 0, wave, lane);
    layer32<16, 8, 4, 0>(P.w + OFF_H0, nullptr, P.b_h0, X, P.out, p0, wave, 0, wave, lane);
    layer32<16, 8, 4, 0>(P.w + OFF_H1, nullptr, P.b_h1, X, P.out, p0, wave, 0, wave, lane);
    layer32<16, 8, 4, 0>(P.w + OFF_H2, nullptr, P.b_h2, X, P.out, p0, wave, 0, wave, lane);
    layer32<16, 8, 4, 0>(P.w + OFF_H3, nullptr, P.b_h3, X, P.out, p0, wave, 0, wave, lane);
    layer32<20, 8, 4, 0>(P.w + OFF_H4, nullptr, P.b_h4, X, P.out, p0, wave, 0, wave, lane); // concat

    // DE splice into groups 32..35: h4's BAR2 closed all reads of 32..39;
    // h4's epilogue and this splice write disjoint groups; h5's BAR1
    // publishes both. Cols 283..287 are real zeros (de_v zero for d >= 27).
    *(bf16x8*)(X + ((size_t)(32 + gD) * 128 + ptD) * 8) = de_v;

    layer32<16, 8, 4, 0>(P.w + OFF_H5, nullptr, P.b_h5, X, P.out, p0, wave, 0, wave, lane);
    layer32<16, 8, 4, 0>(P.w + OFF_H6, nullptr, P.b_h6, X, P.out, p0, wave, 0, wave, lane);
    layer32<16, 8, 4, 1>(P.w + OFF_OUT, P.w + OFF_OUTD, P.b_out, X, P.out, p0, wave, 0, wave, lane);

    // r1 (K=288 -> 128): nb = wave&3, m-half = wave>>2 (2 m-blocks each)
    layer32<18, 4, 2, 0>(P.w + OFF_R1, nullptr, P.b_r1, X, P.out, p0, wave & 3, (wave >> 2) * 2, wave, lane);

    // ---- r2 (128 -> 3) + sigmoid; 16x16, 8 waves, one 16-pt tile each ----
    __syncthreads();
    {
        const int l15 = lane & 15, quad = lane >> 4;
        f32x4 acc = (f32x4){0.f, 0.f, 0.f, 0.f};
        const short* xb = X + quad * 1024 + (wave * 16 + l15) * 8;
#pragma unroll
        for (int kt = 0; kt < 4; ++kt) {
            bf16x8 b = *(const bf16x8*)(xb + kt * 4096);
            bf16x8 a = *(const bf16x8*)(P.w + OFF_R2 + (size_t)(kt * 64 + lane) * 8);
            acc = __builtin_amdgcn_mfma_f32_16x16x32_bf16(a, b, acc, 0, 0, 0);
        }
        if (quad == 0) {                   // rows r = rgb channel
#pragma unroll
            for (int r = 0; r < 3; r++) {
                const float v = acc[r] + P.b_r2[r];
                P.out[(size_t)(p0 + wave * 16 + l15) * 3 + r] = 1.f / (1.f + expf(-v));
            }
        }
    }
}

extern "C" void kernel_launch(void* const* d_in, const int* in_sizes, int n_in,
                              void* d_out, int out_size, void* d_ws, size_t ws_size,
                              hipStream_t stream) {
    short* ws = (short*)d_ws;

    PrepP pp;
    pp.W[0]  = (const float*)d_in[2];   // W_in
    pp.W[1]  = (const float*)d_in[4];   // W_h0
    pp.W[2]  = (const float*)d_in[6];   // W_h1
    pp.W[3]  = (const float*)d_in[8];   // W_h2
    pp.W[4]  = (const float*)d_in[10];  // W_h3
    pp.W[5]  = (const float*)d_in[12];  // W_h4
    pp.W[6]  = (const float*)d_in[14];  // W_h5
    pp.W[7]  = (const float*)d_in[16];  // W_h6
    pp.W[8]  = (const float*)d_in[18];  // W_out
    pp.W[9]  = (const float*)d_in[20];  // W_r1
    pp.W[10] = (const float*)d_in[22];  // W_r2
    pp.ws = ws;
    hipLaunchKernelGGL(prep_all, dim3((WS_TOTAL + 255) / 256), dim3(256), 0, stream, pp);

    Params P;
    P.pos  = (const float*)d_in[0];
    P.dir  = (const float*)d_in[1];
    P.b_in = (const float*)d_in[3];
    P.b_h0 = (const float*)d_in[5];
    P.b_h1 = (const float*)d_in[7];
    P.b_h2 = (const float*)d_in[9];
    P.b_h3 = (const float*)d_in[11];
    P.b_h4 = (const float*)d_in[13];
    P.b_h5 = (const float*)d_in[15];
    P.b_h6 = (const float*)d_in[17];
    P.b_out = (const float*)d_in[19];
    P.b_r1 = (const float*)d_in[21];
    P.b_r2 = (const float*)d_in[23];
    P.w = ws;
    P.out = (float*)d_out;
    hipLaunchKernelGGL(nerf_fused, dim3(NPTS / MT), dim3(512), 0, stream, P);
}